// Round 3
// baseline (661.530 us; speedup 1.0000x reference)
//
#include <hip/hip_runtime.h>
#include <cmath>

typedef unsigned short u16;
typedef unsigned int   u32;
typedef __attribute__((ext_vector_type(8))) __bf16 bf16x8;
typedef __attribute__((ext_vector_type(4))) float  f32x4;
typedef __attribute__((ext_vector_type(8))) unsigned short u16x8;
typedef __attribute__((ext_vector_type(4))) unsigned short u16x4;

#define DEV __device__ __forceinline__

DEV float bf2f(u16 u){ union{u32 i; float f;} v; v.i=((u32)u)<<16; return v.f; }
DEV u16 f2bf(float f){ union{float f; u32 i;} v; v.f=f; u32 r=v.i+0x7fffu+((v.i>>16)&1u); return (u16)(r>>16); }

#if defined(__has_builtin) && __has_builtin(__builtin_amdgcn_global_load_lds)
DEV void gld16(const void* g, void* l){
  __builtin_amdgcn_global_load_lds((__attribute__((address_space(1))) void*)g,
                                   (__attribute__((address_space(3))) void*)l, 16, 0, 0);
}
#else
DEV void gld16(const void* g, void* l){ *(u16x8*)l = *(const u16x8*)g; }
#endif

// ---------------------------------------------------------------------------
// Runtime dtype probe: bf16 N(0,1) data -> ~64/64 sane exponent fields;
// fp32 data read as u16 -> only odd halves sane (~38/64). flag=1 means fp32.
// ---------------------------------------------------------------------------
__global__ void detect_k(const u16* __restrict__ x, int* __restrict__ flag)
{
  if (threadIdx.x == 0 && blockIdx.x == 0){
    int sane = 0;
    for (int i = 0; i < 64; ++i){
      int e = (x[i] >> 7) & 0xFF;
      sane += (e >= 100 && e <= 150);
    }
    *flag = (sane < 56) ? 1 : 0;
  }
}

// Canonicalize the 8 small vectors (gammas/betas/biases) to fp32.
// Layout in dst: [ln1_g 0 | ln1_b 512 | bqkv 1024 | bm 6144 | ln2_g 6656 |
//                 ln2_b 7168 | b1 7680 | b2 9728]  total 10240.
__global__ __launch_bounds__(256)
void conv_vecs(const void* a0,const void* a1,const void* a2,const void* a3,
               const void* a4,const void* a5,const void* a6,const void* a7,
               float* __restrict__ dst, const int* __restrict__ flag)
{
  int i = blockIdx.x*256 + threadIdx.x;
  if (i >= 10240) return;
  const void* src; int off;
  if      (i < 512)  { src=a0; off=i; }
  else if (i < 1024) { src=a1; off=i-512; }
  else if (i < 6144) { src=a2; off=i-1024; }
  else if (i < 6656) { src=a3; off=i-6144; }
  else if (i < 7168) { src=a4; off=i-6656; }
  else if (i < 7680) { src=a5; off=i-7168; }
  else if (i < 9728) { src=a6; off=i-7680; }
  else               { src=a7; off=i-9728; }
  dst[i] = (*flag) ? ((const float*)src)[off] : bf2f(((const u16*)src)[off]);
}

// ---------------------------------------------------------------------------
// Generic 128x128-tile bf16 GEMM, A row-major (M x K), BT row-major (N x K).
// MODE 0: out bf16 = acc + bias
// MODE 1: out f32  = acc + bias + residual (dtype per flag)   (x2)
// MODE 2: out bf16 = swish(acc + bias)
// MODE 3: out (dtype per flag) = acc + bias + f32 residual    (final)
// bias is canonical fp32.
// ---------------------------------------------------------------------------
template<int MODE>
__global__ __launch_bounds__(256)
void gemm_bt(const u16* __restrict__ A, const u16* __restrict__ BT,
             void* __restrict__ C, const float* __restrict__ bias,
             const void* __restrict__ res,
             int K, int lda, int ldb, int ldc, const int* __restrict__ flag)
{
  __shared__ u16 As[128*64];
  __shared__ u16 Bs[128*64];
  const int tid  = threadIdx.x;
  const int lane = tid & 63;
  const int wv   = tid >> 6;
  const int wm   = wv >> 1, wn = wv & 1;
  const long m0 = (long)blockIdx.y * 128;
  const long n0 = (long)blockIdx.x * 128;
  const bool f32io = flag && (*flag != 0);

  f32x4 acc[4][4];
#pragma unroll
  for (int i=0;i<4;i++)
#pragma unroll
    for (int j=0;j<4;j++) acc[i][j] = (f32x4){0.f,0.f,0.f,0.f};

  for (int k0=0; k0<K; k0+=64){
    __syncthreads();
#pragma unroll
    for (int i=0;i<4;i++){
      int c = i*256 + tid;
      gld16(A  + (m0 + (c>>3))*lda + k0 + (c&7)*8, &As[c*8]);
      gld16(BT + (n0 + (c>>3))*ldb + k0 + (c&7)*8, &Bs[c*8]);
    }
    __syncthreads();
#pragma unroll
    for (int kk=0;kk<2;kk++){
      bf16x8 af[4], bfr[4];
#pragma unroll
      for (int t=0;t<4;t++){
        af[t]  = *(const bf16x8*)&As[(wm*64 + t*16 + (lane&15))*64 + kk*32 + (lane>>4)*8];
        bfr[t] = *(const bf16x8*)&Bs[(wn*64 + t*16 + (lane&15))*64 + kk*32 + (lane>>4)*8];
      }
#pragma unroll
      for (int ti=0;ti<4;ti++)
#pragma unroll
        for (int tj=0;tj<4;tj++)
          acc[ti][tj] = __builtin_amdgcn_mfma_f32_16x16x32_bf16(af[ti], bfr[tj], acc[ti][tj], 0,0,0);
    }
  }

#pragma unroll
  for (int ti=0;ti<4;ti++)
#pragma unroll
  for (int tj=0;tj<4;tj++)
#pragma unroll
  for (int r=0;r<4;r++){
    long row = m0 + wm*64 + ti*16 + (lane>>4)*4 + r;
    long col = n0 + wn*64 + tj*16 + (lane&15);
    float v = acc[ti][tj][r] + bias[col];
    if (MODE==0){
      ((u16*)C)[row*ldc+col] = f2bf(v);
    } else if (MODE==1){
      v += f32io ? ((const float*)res)[row*ldc+col]
                 : bf2f(((const u16*)res)[row*ldc+col]);
      ((float*)C)[row*ldc+col] = v;
    } else if (MODE==2){
      v = v / (1.f + __expf(-v));
      ((u16*)C)[row*ldc+col] = f2bf(v);
    } else {
      v += ((const float*)res)[row*ldc+col];
      if (f32io) ((float*)C)[row*ldc+col] = v;
      else       ((u16*)C)[row*ldc+col]   = f2bf(v);
    }
  }
}

// ---------------------------------------------------------------------------
// Attention pass 1: per-row scaled max m and denom l (online over K tiles).
// grid (N/128, B*H), block 256.
// ---------------------------------------------------------------------------
__global__ __launch_bounds__(256)
void att_stats(const u16* __restrict__ qkv, float* __restrict__ mg, float* __restrict__ lg)
{
  __shared__ u16 Qs[128*64];
  __shared__ u16 Ks[128*64];
  __shared__ float pmax[2][128], psum[2][128], run_m[128], run_l[128];
  const int tid=threadIdx.x, lane=tid&63, wv=tid>>6, wm=wv>>1, wn=wv&1;
  const int bh=blockIdx.y, b=bh>>3, h=bh&7;
  const long q0=(long)blockIdx.x*128;
  const u16* qb = qkv + ((long)b*2048 + q0)*5120 + h*64;
  const u16* kb = qkv + (long)b*2048*5120 + 512 + h*64;

#pragma unroll
  for (int i=0;i<4;i++){ int c=i*256+tid; gld16(qb + (long)(c>>3)*5120 + (c&7)*8, &Qs[c*8]); }
  if (tid<128){ run_m[tid] = -1e30f; run_l[tid] = 0.f; }

  for (int mt=0; mt<16; ++mt){
    __syncthreads();
#pragma unroll
    for (int i=0;i<4;i++){ int c=i*256+tid; gld16(kb + (long)(mt*128 + (c>>3))*5120 + (c&7)*8, &Ks[c*8]); }
    __syncthreads();

    f32x4 acc[4][4];
#pragma unroll
    for (int i=0;i<4;i++)
#pragma unroll
      for (int j=0;j<4;j++) acc[i][j] = (f32x4){0.f,0.f,0.f,0.f};
#pragma unroll
    for (int kk=0;kk<2;kk++){
      bf16x8 af[4], bfr[4];
#pragma unroll
      for (int t=0;t<4;t++){
        af[t]  = *(const bf16x8*)&Qs[(wm*64 + t*16 + (lane&15))*64 + kk*32 + (lane>>4)*8];
        bfr[t] = *(const bf16x8*)&Ks[(wn*64 + t*16 + (lane&15))*64 + kk*32 + (lane>>4)*8];
      }
#pragma unroll
      for (int ti=0;ti<4;ti++)
#pragma unroll
        for (int tj=0;tj<4;tj++)
          acc[ti][tj] = __builtin_amdgcn_mfma_f32_16x16x32_bf16(af[ti], bfr[tj], acc[ti][tj], 0,0,0);
    }

#pragma unroll
    for (int ti=0;ti<4;ti++)
#pragma unroll
    for (int r=0;r<4;r++){
      float vm = fmaxf(fmaxf(acc[ti][0][r],acc[ti][1][r]), fmaxf(acc[ti][2][r],acc[ti][3][r]));
      vm = fmaxf(vm, __shfl_xor(vm,1)); vm = fmaxf(vm, __shfl_xor(vm,2));
      vm = fmaxf(vm, __shfl_xor(vm,4)); vm = fmaxf(vm, __shfl_xor(vm,8));
      if ((lane&15)==0) pmax[wn][wm*64 + ti*16 + (lane>>4)*4 + r] = vm;
    }
    __syncthreads();
    if (tid<128){
      float t  = fmaxf(pmax[0][tid], pmax[1][tid]) * 0.125f;
      float om = run_m[tid];
      float nm = fmaxf(om, t);
      run_l[tid] *= __expf(om - nm);
      run_m[tid]  = nm;
    }
    __syncthreads();
#pragma unroll
    for (int ti=0;ti<4;ti++)
#pragma unroll
    for (int r=0;r<4;r++){
      int row = wm*64 + ti*16 + (lane>>4)*4 + r;
      float nm = run_m[row];
      float s = 0.f;
#pragma unroll
      for (int tj=0;tj<4;tj++) s += __expf(acc[ti][tj][r]*0.125f - nm);
      s += __shfl_xor(s,1); s += __shfl_xor(s,2);
      s += __shfl_xor(s,4); s += __shfl_xor(s,8);
      if ((lane&15)==0) psum[wn][row] = s;
    }
    __syncthreads();
    if (tid<128) run_l[tid] += psum[0][tid] + psum[1][tid];
  }
  __syncthreads();
  if (tid<128){
    mg[(long)bh*2048 + q0 + tid] = run_m[tid];
    lg[(long)bh*2048 + q0 + tid] = run_l[tid];
  }
}

// ---------------------------------------------------------------------------
// Attention pass 2: O = softmax(QK^T*scale) @ V, per (c-tile 128, q-tile 128, bh).
// grid (4, 16, 16), block 256.
// ---------------------------------------------------------------------------
__global__ __launch_bounds__(256)
void att_out(const u16* __restrict__ qkv, const u16* __restrict__ vt,
             const float* __restrict__ mg, const float* __restrict__ lg,
             u16* __restrict__ ao)
{
  __shared__ u16 Qs[128*64];
  __shared__ u16 Ks[64*64];
  __shared__ u16 Ps[128*68];   // padded row; rows 8B-aligned -> read via 2x b64
  __shared__ u16 Vs[128*64];
  const int tid=threadIdx.x, lane=tid&63, wv=tid>>6, wm=wv>>1, wn=wv&1;
  const int bh=blockIdx.z, b=bh>>3, h=bh&7;
  const long q0=(long)blockIdx.y*128, c0=(long)blockIdx.x*128;
  const u16* qb = qkv + ((long)b*2048 + q0)*5120 + h*64;
  const u16* kb = qkv + (long)b*2048*5120 + 512 + h*64;
  const u16* vb = vt + (long)bh*512*2048;

#pragma unroll
  for (int i=0;i<4;i++){ int c=i*256+tid; gld16(qb + (long)(c>>3)*5120 + (c&7)*8, &Qs[c*8]); }

  float rm[2][4], rl[2][4];
#pragma unroll
  for (int ti=0;ti<2;ti++)
#pragma unroll
  for (int r=0;r<4;r++){
    long row = (long)bh*2048 + q0 + wv*32 + ti*16 + (lane>>4)*4 + r;
    rm[ti][r] = mg[row];
    rl[ti][r] = 1.f / lg[row];
  }

  f32x4 o[4][4];
#pragma unroll
  for (int i=0;i<4;i++)
#pragma unroll
    for (int j=0;j<4;j++) o[i][j] = (f32x4){0.f,0.f,0.f,0.f};

  for (int mt=0; mt<32; ++mt){
    const long m0 = (long)mt*64;
    __syncthreads();
#pragma unroll
    for (int i=0;i<2;i++){ int c=i*256+tid; gld16(kb + (m0 + (c>>3))*5120 + (c&7)*8, &Ks[c*8]); }
#pragma unroll
    for (int i=0;i<4;i++){ int c=i*256+tid; gld16(vb + (c0 + (c>>3))*2048 + m0 + (c&7)*8, &Vs[c*8]); }
    __syncthreads();

    f32x4 s[2][4];
#pragma unroll
    for (int i=0;i<2;i++)
#pragma unroll
      for (int j=0;j<4;j++) s[i][j] = (f32x4){0.f,0.f,0.f,0.f};
#pragma unroll
    for (int kk=0;kk<2;kk++){
      bf16x8 af[2], bfr[4];
#pragma unroll
      for (int ti=0;ti<2;ti++)
        af[ti] = *(const bf16x8*)&Qs[(wv*32 + ti*16 + (lane&15))*64 + kk*32 + (lane>>4)*8];
#pragma unroll
      for (int tj=0;tj<4;tj++)
        bfr[tj] = *(const bf16x8*)&Ks[(tj*16 + (lane&15))*64 + kk*32 + (lane>>4)*8];
#pragma unroll
      for (int ti=0;ti<2;ti++)
#pragma unroll
        for (int tj=0;tj<4;tj++)
          s[ti][tj] = __builtin_amdgcn_mfma_f32_16x16x32_bf16(af[ti], bfr[tj], s[ti][tj], 0,0,0);
    }

#pragma unroll
    for (int ti=0;ti<2;ti++)
#pragma unroll
    for (int tj=0;tj<4;tj++)
#pragma unroll
    for (int r=0;r<4;r++){
      float arg = fminf(s[ti][tj][r]*0.125f - rm[ti][r], 0.f);
      float p = __expf(arg) * rl[ti][r];
      Ps[(wv*32 + ti*16 + (lane>>4)*4 + r)*68 + tj*16 + (lane&15)] = f2bf(p);
    }
    __syncthreads();

#pragma unroll
    for (int kk=0;kk<2;kk++){
      bf16x8 af[4], bfr[4];
#pragma unroll
      for (int t=0;t<4;t++){
        int base = (wm*64 + t*16 + (lane&15))*68 + kk*32 + (lane>>4)*8;
        union { u16x4 h[2]; bf16x8 v; } u;
        u.h[0] = *(const u16x4*)&Ps[base];
        u.h[1] = *(const u16x4*)&Ps[base+4];
        af[t]  = u.v;
        bfr[t] = *(const bf16x8*)&Vs[(wn*64 + t*16 + (lane&15))*64 + kk*32 + (lane>>4)*8];
      }
#pragma unroll
      for (int ti=0;ti<4;ti++)
#pragma unroll
        for (int tj=0;tj<4;tj++)
          o[ti][tj] = __builtin_amdgcn_mfma_f32_16x16x32_bf16(af[ti], bfr[tj], o[ti][tj], 0,0,0);
    }
  }

#pragma unroll
  for (int ti=0;ti<4;ti++)
#pragma unroll
  for (int tj=0;tj<4;tj++)
#pragma unroll
  for (int r=0;r<4;r++){
    long rown = q0 + wm*64 + ti*16 + (lane>>4)*4 + r;
    long col  = c0 + wn*64 + tj*16 + (lane&15);
    ao[((long)b*2048 + rown)*4096 + (long)h*512 + col] = f2bf(o[ti][tj][r]);
  }
}

// ---------------------------------------------------------------------------
// LayerNorm: one wave per row of 512. SRC=0: input dtype per flag (x),
// SRC=1: fp32 input (x2). gamma/beta are canonical fp32.
// ---------------------------------------------------------------------------
template<int SRC>
__global__ __launch_bounds__(256)
void ln_kernel(const void* __restrict__ xin, const float* __restrict__ g,
               const float* __restrict__ bb, u16* __restrict__ out,
               const int* __restrict__ flag)
{
  const int tid=threadIdx.x, lane=tid&63, wv=tid>>6;
  const long row = (long)blockIdx.x*4 + wv;
  const bool f32 = (SRC==1) || (flag && *flag != 0);
  float v[8];
  if (f32){
    const float* xr = (const float*)xin + row*512 + lane*8;
#pragma unroll
    for (int j=0;j<8;j++) v[j]=xr[j];
  } else {
    const u16* xr = (const u16*)xin + row*512 + lane*8;
    u16x8 xv = *(const u16x8*)xr;
#pragma unroll
    for (int j=0;j<8;j++) v[j]=bf2f(xv[j]);
  }
  float s1=0.f, s2=0.f;
#pragma unroll
  for (int j=0;j<8;j++){ s1+=v[j]; s2+=v[j]*v[j]; }
  for (int off=1; off<64; off<<=1){ s1+=__shfl_xor(s1,off); s2+=__shfl_xor(s2,off); }
  float mu  = s1*(1.f/512.f);
  float var = s2*(1.f/512.f) - mu*mu;
  float rs  = rsqrtf(var + 1e-5f);
  u16x8 ov;
#pragma unroll
  for (int j=0;j<8;j++){
    int col = lane*8+j;
    ov[j] = f2bf((v[j]-mu)*rs*g[col] + bb[col]);
  }
  *(u16x8*)(out + row*512 + lane*8) = ov;
}

// ---------------------------------------------------------------------------
// Tiled transpose -> bf16 out. DUAL: input dtype per flag (weights);
// DUAL=false: bf16 input (vtb path). Per-z in-offset (z>>3)*izh+(z&7)*izl (elems).
// grid (C/32, R/32, Z), block (32,8).
// ---------------------------------------------------------------------------
template<bool DUAL>
__global__ __launch_bounds__(256)
void transpose_k(const void* __restrict__ in_, u16* __restrict__ out,
                 int ldi, int ldo, long izh, long izl, long oz,
                 const int* __restrict__ flag)
{
  __shared__ u16 t[32][33];
  const int z = blockIdx.z;
  const bool f32 = DUAL && flag && (*flag != 0);
  const long zoff = (long)(z>>3)*izh + (long)(z&7)*izl;
  out += (long)z*oz;
  const int tx = threadIdx.x, ty = threadIdx.y;
  const long c  = (long)blockIdx.x*32 + tx;
  const long r0 = (long)blockIdx.y*32;
  if (f32){
    const float* in = (const float*)in_ + zoff;
#pragma unroll
    for (int j=0;j<4;j++) t[ty+j*8][tx] = f2bf(in[(r0+ty+j*8)*ldi + c]);
  } else {
    const u16* in = (const u16*)in_ + zoff;
#pragma unroll
    for (int j=0;j<4;j++) t[ty+j*8][tx] = in[(r0+ty+j*8)*ldi + c];
  }
  __syncthreads();
  const long rr = r0 + tx;
  const long cc = (long)blockIdx.x*32 + ty;
#pragma unroll
  for (int j=0;j<4;j++) out[(cc+j*8)*ldo + rr] = t[tx][ty+j*8];
}

// ---------------------------------------------------------------------------
extern "C" void kernel_launch(void* const* d_in, const int* in_sizes, int n_in,
                              void* d_out, int out_size, void* d_ws, size_t ws_size,
                              hipStream_t stream)
{
  const void* x    = d_in[0];
  const void* ln1g = d_in[1];
  const void* ln1b = d_in[2];
  const void* Wqkv = d_in[3];
  const void* bqkv = d_in[4];
  const void* Wm   = d_in[5];
  const void* bm   = d_in[6];
  const void* ln2g = d_in[7];
  const void* ln2b = d_in[8];
  const void* W1   = d_in[9];
  const void* b1   = d_in[10];
  const void* W2   = d_in[11];
  const void* b2   = d_in[12];

  char* p = (char*)d_ws;
  auto take = [&](size_t n){ void* r=(void*)p; p += (n + 255) & ~(size_t)255; return r; };
  u16*   lnb   = (u16*)  take((size_t)4096*512*2);       // ln1 out, later ln2 out
  u16*   qkv   = (u16*)  take((size_t)4096*5120*2);      // q|k|v rows; later hb
  u16*   vtb   = (u16*)  take((size_t)16*512*2048*2);    // per-head V^T; later x2
  u16*   wqkvT = (u16*)  take((size_t)5120*512*2);
  u16*   wmT   = (u16*)  take((size_t)512*4096*2);
  u16*   w1T   = (u16*)  take((size_t)2048*512*2);
  u16*   w2T   = (u16*)  take((size_t)512*2048*2);
  float* mgb   = (float*)take((size_t)16*2048*4);
  float* lgb   = (float*)take((size_t)16*2048*4);
  u16*   ao    = (u16*)  take((size_t)4096*4096*2);      // attention out (B*N, H*512)
  float* cvec  = (float*)take((size_t)10240*4);          // canonical fp32 small vectors
  int*   flag  = (int*)  take(4);
  float* x2    = (float*)vtb;                            // overlay: vtb dead after att_out
  u16*   hb    = qkv;                                    // overlay: qkv dead after attention

  // dtype probe + canonical small vectors
  detect_k<<<1, 64, 0, stream>>>((const u16*)x, flag);
  conv_vecs<<<40, 256, 0, stream>>>(ln1g, ln1b, bqkv, bm, ln2g, ln2b, b1, b2, cvec, flag);

  dim3 tb(32,8);
  // Weight transposes (BT-form for the GEMM B operand), dual-dtype
  transpose_k<true><<<dim3(160,16,1), tb, 0, stream>>>(Wqkv, wqkvT, 5120, 512, 0,0,0, flag);
  transpose_k<true><<<dim3(16,128,1), tb, 0, stream>>>(Wm,   wmT,   512, 4096, 0,0,0, flag);
  transpose_k<true><<<dim3(64,16,1),  tb, 0, stream>>>(W1,   w1T,  2048, 512, 0,0,0, flag);
  transpose_k<true><<<dim3(16,64,1),  tb, 0, stream>>>(W2,   w2T,   512, 2048, 0,0,0, flag);

  // ln1 -> qkv
  ln_kernel<0><<<1024, 256, 0, stream>>>(x, cvec+0, cvec+512, lnb, flag);
  gemm_bt<0><<<dim3(40,32), 256, 0, stream>>>(lnb, wqkvT, qkv, cvec+1024, nullptr,
                                              512, 512, 512, 5120, nullptr);

  // per-head V^T (bf16 source: our own qkv)
  transpose_k<false><<<dim3(16,64,16), tb, 0, stream>>>(qkv + 1024, vtb, 5120, 2048,
                                                        (long)2048*5120, 512, (long)512*2048, nullptr);
  // attention
  att_stats<<<dim3(16,16), 256, 0, stream>>>(qkv, mgb, lgb);
  att_out<<<dim3(4,16,16), 256, 0, stream>>>(qkv, vtb, mgb, lgb, ao);

  // x2 = x + ao@Wm + bm  (fp32; residual dtype per flag)
  gemm_bt<1><<<dim3(4,32), 256, 0, stream>>>(ao, wmT, x2, cvec+6144, x,
                                             4096, 4096, 4096, 512, flag);
  // ln2, MLP
  ln_kernel<1><<<1024, 256, 0, stream>>>(x2, cvec+6656, cvec+7168, lnb, nullptr);
  gemm_bt<2><<<dim3(16,32), 256, 0, stream>>>(lnb, w1T, hb, cvec+7680, nullptr,
                                              512, 512, 512, 2048, nullptr);
  gemm_bt<3><<<dim3(4,32), 256, 0, stream>>>(hb, w2T, d_out, cvec+9728, x2,
                                             2048, 2048, 2048, 512, flag);
}

// Round 4
// 558.024 us; speedup vs baseline: 1.1855x; 1.1855x over previous
//
#include <hip/hip_runtime.h>
#include <cmath>

typedef unsigned short u16;
typedef unsigned int   u32;
typedef __attribute__((ext_vector_type(8))) __bf16 bf16x8;
typedef __attribute__((ext_vector_type(4))) float  f32x4;
typedef __attribute__((ext_vector_type(8))) unsigned short u16x8;
typedef __attribute__((ext_vector_type(4))) unsigned short u16x4;

#define DEV __device__ __forceinline__

DEV float bf2f(u16 u){ union{u32 i; float f;} v; v.i=((u32)u)<<16; return v.f; }
DEV u16 f2bf(float f){ union{float f; u32 i;} v; v.f=f; u32 r=v.i+0x7fffu+((v.i>>16)&1u); return (u16)(r>>16); }

#if defined(__has_builtin) && __has_builtin(__builtin_amdgcn_global_load_lds)
DEV void gld16(const void* g, void* l){
  __builtin_amdgcn_global_load_lds((__attribute__((address_space(1))) void*)g,
                                   (__attribute__((address_space(3))) void*)l, 16, 0, 0);
}
#else
DEV void gld16(const void* g, void* l){ *(u16x8*)l = *(const u16x8*)g; }
#endif

// ---------------------------------------------------------------------------
// Runtime dtype probe (flag=1 -> fp32 inputs). Round 3 confirmed fp32.
// ---------------------------------------------------------------------------
__global__ void detect_k(const u16* __restrict__ x, int* __restrict__ flag)
{
  if (threadIdx.x == 0 && blockIdx.x == 0){
    int sane = 0;
    for (int i = 0; i < 64; ++i){
      int e = (x[i] >> 7) & 0xFF;
      sane += (e >= 100 && e <= 150);
    }
    *flag = (sane < 56) ? 1 : 0;
  }
}

// Canonicalize the 8 small vectors (gammas/betas/biases) to fp32.
// dst layout: [ln1_g 0 | ln1_b 512 | bqkv 1024 | bm 6144 | ln2_g 6656 |
//              ln2_b 7168 | b1 7680 | b2 9728]  total 10240.
__global__ __launch_bounds__(256)
void conv_vecs(const void* a0,const void* a1,const void* a2,const void* a3,
               const void* a4,const void* a5,const void* a6,const void* a7,
               float* __restrict__ dst, const int* __restrict__ flag)
{
  int i = blockIdx.x*256 + threadIdx.x;
  if (i >= 10240) return;
  const void* src; int off;
  if      (i < 512)  { src=a0; off=i; }
  else if (i < 1024) { src=a1; off=i-512; }
  else if (i < 6144) { src=a2; off=i-1024; }
  else if (i < 6656) { src=a3; off=i-6144; }
  else if (i < 7168) { src=a4; off=i-6656; }
  else if (i < 7680) { src=a5; off=i-7168; }
  else if (i < 9728) { src=a6; off=i-7680; }
  else               { src=a7; off=i-9728; }
  dst[i] = (*flag) ? ((const float*)src)[off] : bf2f(((const u16*)src)[off]);
}

// ---------------------------------------------------------------------------
// 128x128-tile bf16 GEMM, A row-major (M x K), BT row-major (N x K).
// MODE 0: out bf16 = acc + bias
// MODE 2: out bf16 = swish(acc + bias)
// ---------------------------------------------------------------------------
template<int MODE>
__global__ __launch_bounds__(256)
void gemm_bt(const u16* __restrict__ A, const u16* __restrict__ BT,
             void* __restrict__ C, const float* __restrict__ bias,
             int K, int lda, int ldb, int ldc)
{
  __shared__ u16 As[128*64];
  __shared__ u16 Bs[128*64];
  const int tid  = threadIdx.x;
  const int lane = tid & 63;
  const int wv   = tid >> 6;
  const int wm   = wv >> 1, wn = wv & 1;
  const long m0 = (long)blockIdx.y * 128;
  const long n0 = (long)blockIdx.x * 128;

  f32x4 acc[4][4];
#pragma unroll
  for (int i=0;i<4;i++)
#pragma unroll
    for (int j=0;j<4;j++) acc[i][j] = (f32x4){0.f,0.f,0.f,0.f};

  for (int k0=0; k0<K; k0+=64){
    __syncthreads();
#pragma unroll
    for (int i=0;i<4;i++){
      int c = i*256 + tid;
      gld16(A  + (m0 + (c>>3))*lda + k0 + (c&7)*8, &As[c*8]);
      gld16(BT + (n0 + (c>>3))*ldb + k0 + (c&7)*8, &Bs[c*8]);
    }
    __syncthreads();
#pragma unroll
    for (int kk=0;kk<2;kk++){
      bf16x8 af[4], bfr[4];
#pragma unroll
      for (int t=0;t<4;t++){
        af[t]  = *(const bf16x8*)&As[(wm*64 + t*16 + (lane&15))*64 + kk*32 + (lane>>4)*8];
        bfr[t] = *(const bf16x8*)&Bs[(wn*64 + t*16 + (lane&15))*64 + kk*32 + (lane>>4)*8];
      }
#pragma unroll
      for (int ti=0;ti<4;ti++)
#pragma unroll
        for (int tj=0;tj<4;tj++)
          acc[ti][tj] = __builtin_amdgcn_mfma_f32_16x16x32_bf16(af[ti], bfr[tj], acc[ti][tj], 0,0,0);
    }
  }

#pragma unroll
  for (int ti=0;ti<4;ti++)
#pragma unroll
  for (int tj=0;tj<4;tj++)
#pragma unroll
  for (int r=0;r<4;r++){
    long row = m0 + wm*64 + ti*16 + (lane>>4)*4 + r;
    long col = n0 + wn*64 + tj*16 + (lane&15);
    float v = acc[ti][tj][r] + bias[col];
    if (MODE==2) v = v / (1.f + __expf(-v));
    ((u16*)C)[row*ldc+col] = f2bf(v);
  }
}

// ---------------------------------------------------------------------------
// 128x64-tile bf16 GEMM for narrow-N outputs (N=512): 2x the blocks.
// MODE 1: out f32 = acc + bias + residual (dtype per flag)   (x2)
// MODE 3: out (dtype per flag) = acc + bias + f32 residual   (final)
// ---------------------------------------------------------------------------
template<int MODE>
__global__ __launch_bounds__(256)
void gemm_n64(const u16* __restrict__ A, const u16* __restrict__ BT,
              void* __restrict__ C, const float* __restrict__ bias,
              const void* __restrict__ res,
              int K, int lda, int ldb, int ldc, const int* __restrict__ flag)
{
  __shared__ u16 As[128*64];
  __shared__ u16 Bs[64*64];
  const int tid  = threadIdx.x;
  const int lane = tid & 63;
  const int wm   = tid >> 6;          // 4 waves stacked along M (32 rows each)
  const long m0 = (long)blockIdx.y * 128;
  const long n0 = (long)blockIdx.x * 64;
  const bool f32io = flag && (*flag != 0);

  f32x4 acc[2][4];
#pragma unroll
  for (int i=0;i<2;i++)
#pragma unroll
    for (int j=0;j<4;j++) acc[i][j] = (f32x4){0.f,0.f,0.f,0.f};

  for (int k0=0; k0<K; k0+=64){
    __syncthreads();
#pragma unroll
    for (int i=0;i<4;i++){
      int c = i*256 + tid;
      gld16(A + (m0 + (c>>3))*lda + k0 + (c&7)*8, &As[c*8]);
    }
#pragma unroll
    for (int i=0;i<2;i++){
      int c = i*256 + tid;
      gld16(BT + (n0 + (c>>3))*ldb + k0 + (c&7)*8, &Bs[c*8]);
    }
    __syncthreads();
#pragma unroll
    for (int kk=0;kk<2;kk++){
      bf16x8 af[2], bfr[4];
#pragma unroll
      for (int t=0;t<2;t++)
        af[t]  = *(const bf16x8*)&As[(wm*32 + t*16 + (lane&15))*64 + kk*32 + (lane>>4)*8];
#pragma unroll
      for (int t=0;t<4;t++)
        bfr[t] = *(const bf16x8*)&Bs[(t*16 + (lane&15))*64 + kk*32 + (lane>>4)*8];
#pragma unroll
      for (int ti=0;ti<2;ti++)
#pragma unroll
        for (int tj=0;tj<4;tj++)
          acc[ti][tj] = __builtin_amdgcn_mfma_f32_16x16x32_bf16(af[ti], bfr[tj], acc[ti][tj], 0,0,0);
    }
  }

#pragma unroll
  for (int ti=0;ti<2;ti++)
#pragma unroll
  for (int tj=0;tj<4;tj++)
#pragma unroll
  for (int r=0;r<4;r++){
    long row = m0 + wm*32 + ti*16 + (lane>>4)*4 + r;
    long col = n0 + tj*16 + (lane&15);
    float v = acc[ti][tj][r] + bias[col];
    if (MODE==1){
      v += f32io ? ((const float*)res)[row*ldc+col]
                 : bf2f(((const u16*)res)[row*ldc+col]);
      ((float*)C)[row*ldc+col] = v;
    } else {
      v += ((const float*)res)[row*ldc+col];
      if (f32io) ((float*)C)[row*ldc+col] = v;
      else       ((u16*)C)[row*ldc+col]   = f2bf(v);
    }
  }
}

// ---------------------------------------------------------------------------
// Attention pass 1: per-row scaled max m and denom l (online over K tiles).
// grid (N/128, B*H), block 256.
// ---------------------------------------------------------------------------
__global__ __launch_bounds__(256)
void att_stats(const u16* __restrict__ qkv, float* __restrict__ mg, float* __restrict__ lg)
{
  __shared__ u16 Qs[128*64];
  __shared__ u16 Ks[128*64];
  __shared__ float pmax[2][128], psum[2][128], run_m[128], run_l[128];
  const int tid=threadIdx.x, lane=tid&63, wv=tid>>6, wm=wv>>1, wn=wv&1;
  const int bh=blockIdx.y, b=bh>>3, h=bh&7;
  const long q0=(long)blockIdx.x*128;
  const u16* qb = qkv + ((long)b*2048 + q0)*5120 + h*64;
  const u16* kb = qkv + (long)b*2048*5120 + 512 + h*64;

#pragma unroll
  for (int i=0;i<4;i++){ int c=i*256+tid; gld16(qb + (long)(c>>3)*5120 + (c&7)*8, &Qs[c*8]); }
  if (tid<128){ run_m[tid] = -1e30f; run_l[tid] = 0.f; }

  for (int mt=0; mt<16; ++mt){
    __syncthreads();
#pragma unroll
    for (int i=0;i<4;i++){ int c=i*256+tid; gld16(kb + (long)(mt*128 + (c>>3))*5120 + (c&7)*8, &Ks[c*8]); }
    __syncthreads();

    f32x4 acc[4][4];
#pragma unroll
    for (int i=0;i<4;i++)
#pragma unroll
      for (int j=0;j<4;j++) acc[i][j] = (f32x4){0.f,0.f,0.f,0.f};
#pragma unroll
    for (int kk=0;kk<2;kk++){
      bf16x8 af[4], bfr[4];
#pragma unroll
      for (int t=0;t<4;t++){
        af[t]  = *(const bf16x8*)&Qs[(wm*64 + t*16 + (lane&15))*64 + kk*32 + (lane>>4)*8];
        bfr[t] = *(const bf16x8*)&Ks[(wn*64 + t*16 + (lane&15))*64 + kk*32 + (lane>>4)*8];
      }
#pragma unroll
      for (int ti=0;ti<4;ti++)
#pragma unroll
        for (int tj=0;tj<4;tj++)
          acc[ti][tj] = __builtin_amdgcn_mfma_f32_16x16x32_bf16(af[ti], bfr[tj], acc[ti][tj], 0,0,0);
    }

#pragma unroll
    for (int ti=0;ti<4;ti++)
#pragma unroll
    for (int r=0;r<4;r++){
      float vm = fmaxf(fmaxf(acc[ti][0][r],acc[ti][1][r]), fmaxf(acc[ti][2][r],acc[ti][3][r]));
      vm = fmaxf(vm, __shfl_xor(vm,1)); vm = fmaxf(vm, __shfl_xor(vm,2));
      vm = fmaxf(vm, __shfl_xor(vm,4)); vm = fmaxf(vm, __shfl_xor(vm,8));
      if ((lane&15)==0) pmax[wn][wm*64 + ti*16 + (lane>>4)*4 + r] = vm;
    }
    __syncthreads();
    if (tid<128){
      float t  = fmaxf(pmax[0][tid], pmax[1][tid]) * 0.125f;
      float om = run_m[tid];
      float nm = fmaxf(om, t);
      run_l[tid] *= __expf(om - nm);
      run_m[tid]  = nm;
    }
    __syncthreads();
#pragma unroll
    for (int ti=0;ti<4;ti++)
#pragma unroll
    for (int r=0;r<4;r++){
      int row = wm*64 + ti*16 + (lane>>4)*4 + r;
      float nm = run_m[row];
      float s = 0.f;
#pragma unroll
      for (int tj=0;tj<4;tj++) s += __expf(acc[ti][tj][r]*0.125f - nm);
      s += __shfl_xor(s,1); s += __shfl_xor(s,2);
      s += __shfl_xor(s,4); s += __shfl_xor(s,8);
      if ((lane&15)==0) psum[wn][row] = s;
    }
    __syncthreads();
    if (tid<128) run_l[tid] += psum[0][tid] + psum[1][tid];
  }
  __syncthreads();
  if (tid<128){
    mg[(long)bh*2048 + q0 + tid] = run_m[tid];
    lg[(long)bh*2048 + q0 + tid] = run_l[tid];
  }
}

// ---------------------------------------------------------------------------
// Attention pass 2 v2: O = softmax(QK^T*scale) @ V.
// Block = 512 threads (8 waves); c-width 256; grid (2, 16, 16).
// S (128x64) computed once per k-tile by 8 waves (16 rows each);
// PV: wave grid 2x4, each wave a 64x64 O sub-tile.
// ---------------------------------------------------------------------------
__global__ __launch_bounds__(512, 4)
void att_out2(const u16* __restrict__ qkv, const u16* __restrict__ vt,
              const float* __restrict__ mg, const float* __restrict__ lg,
              u16* __restrict__ ao)
{
  __shared__ u16 Qs[128*64];   // 16 KB
  __shared__ u16 Ks[64*64];    //  8 KB
  __shared__ u16 Ps[128*68];   // 17 KB (padded rows; 8B-aligned -> 2x b64 reads)
  __shared__ u16 Vs[256*64];   // 32 KB
  const int tid=threadIdx.x, lane=tid&63, wv=tid>>6;
  const int wm=wv>>2, wn=wv&3;          // PV wave grid 2x4
  const int quad = lane>>4;
  const int bh=blockIdx.z, b=bh>>3, h=bh&7;
  const long q0=(long)blockIdx.y*128, c0=(long)blockIdx.x*256;
  const u16* qb = qkv + ((long)b*2048 + q0)*5120 + h*64;
  const u16* kb = qkv + (long)b*2048*5120 + 512 + h*64;
  const u16* vb = vt + (long)bh*512*2048;

#pragma unroll
  for (int i=0;i<2;i++){ int c=i*512+tid; gld16(qb + (long)(c>>3)*5120 + (c&7)*8, &Qs[c*8]); }

  // m, l for this wave's S rows (wv*16 + quad*4 + r)
  float rm[4], rl[4];
#pragma unroll
  for (int r=0;r<4;r++){
    long row = (long)bh*2048 + q0 + wv*16 + quad*4 + r;
    rm[r] = mg[row];
    rl[r] = 1.f / lg[row];
  }

  f32x4 o[4][4];
#pragma unroll
  for (int i=0;i<4;i++)
#pragma unroll
    for (int j=0;j<4;j++) o[i][j] = (f32x4){0.f,0.f,0.f,0.f};

  for (int mt=0; mt<32; ++mt){
    const long m0 = (long)mt*64;
    __syncthreads();
    { int c=tid; gld16(kb + (m0 + (c>>3))*5120 + (c&7)*8, &Ks[c*8]); }
#pragma unroll
    for (int i=0;i<4;i++){ int c=i*512+tid; gld16(vb + (c0 + (c>>3))*2048 + m0 + (c&7)*8, &Vs[c*8]); }
    __syncthreads();

    // S rows wv*16..+15, cols 0..63
    f32x4 s[4];
#pragma unroll
    for (int j=0;j<4;j++) s[j] = (f32x4){0.f,0.f,0.f,0.f};
#pragma unroll
    for (int kk=0;kk<2;kk++){
      bf16x8 af = *(const bf16x8*)&Qs[(wv*16 + (lane&15))*64 + kk*32 + quad*8];
#pragma unroll
      for (int tj=0;tj<4;tj++){
        bf16x8 bfr = *(const bf16x8*)&Ks[(tj*16 + (lane&15))*64 + kk*32 + quad*8];
        s[tj] = __builtin_amdgcn_mfma_f32_16x16x32_bf16(af, bfr, s[tj], 0,0,0);
      }
    }

    // P = exp(min(s*scale - m, 0))/l -> bf16 LDS
#pragma unroll
    for (int tj=0;tj<4;tj++)
#pragma unroll
    for (int r=0;r<4;r++){
      float arg = fminf(s[tj][r]*0.125f - rm[r], 0.f);
      float pv = __expf(arg) * rl[r];
      Ps[(wv*16 + quad*4 + r)*68 + tj*16 + (lane&15)] = f2bf(pv);
    }
    __syncthreads();

    // O += P(128x64) * V^T-tile(64x256); wave (wm,wn) -> 64x64
#pragma unroll
    for (int kk=0;kk<2;kk++){
      bf16x8 af[4], bfr[4];
#pragma unroll
      for (int t=0;t<4;t++){
        int base = (wm*64 + t*16 + (lane&15))*68 + kk*32 + quad*8;
        union { u16x4 hh[2]; bf16x8 v; } u;
        u.hh[0] = *(const u16x4*)&Ps[base];
        u.hh[1] = *(const u16x4*)&Ps[base+4];
        af[t]  = u.v;
        bfr[t] = *(const bf16x8*)&Vs[(wn*64 + t*16 + (lane&15))*64 + kk*32 + quad*8];
      }
#pragma unroll
      for (int ti=0;ti<4;ti++)
#pragma unroll
        for (int tj=0;tj<4;tj++)
          o[ti][tj] = __builtin_amdgcn_mfma_f32_16x16x32_bf16(af[ti], bfr[tj], o[ti][tj], 0,0,0);
    }
  }

#pragma unroll
  for (int ti=0;ti<4;ti++)
#pragma unroll
  for (int tj=0;tj<4;tj++)
#pragma unroll
  for (int r=0;r<4;r++){
    long rown = q0 + wm*64 + ti*16 + quad*4 + r;
    long col  = c0 + wn*64 + tj*16 + (lane&15);
    ao[((long)b*2048 + rown)*4096 + (long)h*512 + col] = f2bf(o[ti][tj][r]);
  }
}

// ---------------------------------------------------------------------------
// LayerNorm: one wave per row of 512. SRC=0: input dtype per flag (x),
// SRC=1: fp32 input (x2).
// ---------------------------------------------------------------------------
template<int SRC>
__global__ __launch_bounds__(256)
void ln_kernel(const void* __restrict__ xin, const float* __restrict__ g,
               const float* __restrict__ bb, u16* __restrict__ out,
               const int* __restrict__ flag)
{
  const int tid=threadIdx.x, lane=tid&63, wv=tid>>6;
  const long row = (long)blockIdx.x*4 + wv;
  const bool f32 = (SRC==1) || (flag && *flag != 0);
  float v[8];
  if (f32){
    const float* xr = (const float*)xin + row*512 + lane*8;
#pragma unroll
    for (int j=0;j<8;j++) v[j]=xr[j];
  } else {
    const u16* xr = (const u16*)xin + row*512 + lane*8;
    u16x8 xv = *(const u16x8*)xr;
#pragma unroll
    for (int j=0;j<8;j++) v[j]=bf2f(xv[j]);
  }
  float s1=0.f, s2=0.f;
#pragma unroll
  for (int j=0;j<8;j++){ s1+=v[j]; s2+=v[j]*v[j]; }
  for (int off=1; off<64; off<<=1){ s1+=__shfl_xor(s1,off); s2+=__shfl_xor(s2,off); }
  float mu  = s1*(1.f/512.f);
  float var = s2*(1.f/512.f) - mu*mu;
  float rs  = rsqrtf(var + 1e-5f);
  u16x8 ov;
#pragma unroll
  for (int j=0;j<8;j++){
    int col = lane*8+j;
    ov[j] = f2bf((v[j]-mu)*rs*g[col] + bb[col]);
  }
  *(u16x8*)(out + row*512 + lane*8) = ov;
}

// ---------------------------------------------------------------------------
// Tiled transpose -> bf16 out. DUAL: input dtype per flag (weights);
// DUAL=false: bf16 input (vtb). Per-z in-offset (z>>3)*izh+(z&7)*izl (elems).
// ---------------------------------------------------------------------------
template<bool DUAL>
__global__ __launch_bounds__(256)
void transpose_k(const void* __restrict__ in_, u16* __restrict__ out,
                 int ldi, int ldo, long izh, long izl, long oz,
                 const int* __restrict__ flag)
{
  __shared__ u16 t[32][33];
  const int z = blockIdx.z;
  const bool f32 = DUAL && flag && (*flag != 0);
  const long zoff = (long)(z>>3)*izh + (long)(z&7)*izl;
  out += (long)z*oz;
  const int tx = threadIdx.x, ty = threadIdx.y;
  const long c  = (long)blockIdx.x*32 + tx;
  const long r0 = (long)blockIdx.y*32;
  if (f32){
    const float* in = (const float*)in_ + zoff;
#pragma unroll
    for (int j=0;j<4;j++) t[ty+j*8][tx] = f2bf(in[(r0+ty+j*8)*ldi + c]);
  } else {
    const u16* in = (const u16*)in_ + zoff;
#pragma unroll
    for (int j=0;j<4;j++) t[ty+j*8][tx] = in[(r0+ty+j*8)*ldi + c];
  }
  __syncthreads();
  const long rr = r0 + tx;
  const long cc = (long)blockIdx.x*32 + ty;
#pragma unroll
  for (int j=0;j<4;j++) out[(cc+j*8)*ldo + rr] = t[tx][ty+j*8];
}

// ---------------------------------------------------------------------------
extern "C" void kernel_launch(void* const* d_in, const int* in_sizes, int n_in,
                              void* d_out, int out_size, void* d_ws, size_t ws_size,
                              hipStream_t stream)
{
  const void* x    = d_in[0];
  const void* ln1g = d_in[1];
  const void* ln1b = d_in[2];
  const void* Wqkv = d_in[3];
  const void* bqkv = d_in[4];
  const void* Wm   = d_in[5];
  const void* bm   = d_in[6];
  const void* ln2g = d_in[7];
  const void* ln2b = d_in[8];
  const void* W1   = d_in[9];
  const void* b1   = d_in[10];
  const void* W2   = d_in[11];
  const void* b2   = d_in[12];

  char* p = (char*)d_ws;
  auto take = [&](size_t n){ void* r=(void*)p; p += (n + 255) & ~(size_t)255; return r; };
  u16*   lnb   = (u16*)  take((size_t)4096*512*2);       // ln1 out, later ln2 out
  u16*   qkv   = (u16*)  take((size_t)4096*5120*2);      // q|k|v rows; later hb
  u16*   vtb   = (u16*)  take((size_t)16*512*2048*2);    // per-head V^T; later x2
  u16*   wqkvT = (u16*)  take((size_t)5120*512*2);
  u16*   wmT   = (u16*)  take((size_t)512*4096*2);
  u16*   w1T   = (u16*)  take((size_t)2048*512*2);
  u16*   w2T   = (u16*)  take((size_t)512*2048*2);
  float* mgb   = (float*)take((size_t)16*2048*4);
  float* lgb   = (float*)take((size_t)16*2048*4);
  u16*   ao    = (u16*)  take((size_t)4096*4096*2);      // attention out (B*N, H*512)
  float* cvec  = (float*)take((size_t)10240*4);          // canonical fp32 small vectors
  int*   flag  = (int*)  take(4);
  float* x2    = (float*)vtb;                            // overlay: vtb dead after att_out2
  u16*   hb    = qkv;                                    // overlay: qkv dead after attention

  // dtype probe + canonical small vectors
  detect_k<<<1, 64, 0, stream>>>((const u16*)x, flag);
  conv_vecs<<<40, 256, 0, stream>>>(ln1g, ln1b, bqkv, bm, ln2g, ln2b, b1, b2, cvec, flag);

  dim3 tb(32,8);
  // Weight transposes (BT-form for the GEMM B operand), dual-dtype
  transpose_k<true><<<dim3(160,16,1), tb, 0, stream>>>(Wqkv, wqkvT, 5120, 512, 0,0,0, flag);
  transpose_k<true><<<dim3(16,128,1), tb, 0, stream>>>(Wm,   wmT,   512, 4096, 0,0,0, flag);
  transpose_k<true><<<dim3(64,16,1),  tb, 0, stream>>>(W1,   w1T,  2048, 512, 0,0,0, flag);
  transpose_k<true><<<dim3(16,64,1),  tb, 0, stream>>>(W2,   w2T,   512, 2048, 0,0,0, flag);

  // ln1 -> qkv
  ln_kernel<0><<<1024, 256, 0, stream>>>(x, cvec+0, cvec+512, lnb, flag);
  gemm_bt<0><<<dim3(40,32), 256, 0, stream>>>(lnb, wqkvT, qkv, cvec+1024, 512, 512, 512, 5120);

  // per-head V^T (bf16 source: our own qkv)
  transpose_k<false><<<dim3(16,64,16), tb, 0, stream>>>(qkv + 1024, vtb, 5120, 2048,
                                                        (long)2048*5120, 512, (long)512*2048, nullptr);
  // attention
  att_stats<<<dim3(16,16), 256, 0, stream>>>(qkv, mgb, lgb);
  att_out2<<<dim3(2,16,16), 512, 0, stream>>>(qkv, vtb, mgb, lgb, ao);

  // x2 = x + ao@Wm + bm  (fp32; residual dtype per flag)
  gemm_n64<1><<<dim3(8,32), 256, 0, stream>>>(ao, wmT, x2, cvec+6144, x,
                                              4096, 4096, 4096, 512, flag);
  // ln2, MLP
  ln_kernel<1><<<1024, 256, 0, stream>>>(x2, cvec+6656, cvec+7168, lnb, nullptr);
  gemm_bt<2><<<dim3(16,32), 256, 0, stream>>>(lnb, w1T, hb, cvec+7680, 512, 512, 512, 2048);
  gemm_n64<3><<<dim3(8,32), 256, 0, stream>>>(hb, w2T, d_out, cvec+9728, x2,
                                              2048, 2048, 2048, 512, flag);
}

// Round 5
// 452.000 us; speedup vs baseline: 1.4636x; 1.2346x over previous
//
#include <hip/hip_runtime.h>
#include <cmath>

typedef unsigned short u16;
typedef unsigned int   u32;
typedef __attribute__((ext_vector_type(8))) __bf16 bf16x8;
typedef __attribute__((ext_vector_type(4))) float  f32x4;
typedef __attribute__((ext_vector_type(8))) unsigned short u16x8;
typedef __attribute__((ext_vector_type(4))) unsigned short u16x4;

#define DEV __device__ __forceinline__

DEV float bf2f(u16 u){ union{u32 i; float f;} v; v.i=((u32)u)<<16; return v.f; }
DEV u16 f2bf(float f){ union{float f; u32 i;} v; v.f=f; u32 r=v.i+0x7fffu+((v.i>>16)&1u); return (u16)(r>>16); }

#if defined(__has_builtin) && __has_builtin(__builtin_amdgcn_global_load_lds)
DEV void gld16(const void* g, void* l){
  __builtin_amdgcn_global_load_lds((__attribute__((address_space(1))) void*)g,
                                   (__attribute__((address_space(3))) void*)l, 16, 0, 0);
}
#else
DEV void gld16(const void* g, void* l){ *(u16x8*)l = *(const u16x8*)g; }
#endif

// ---------------------------------------------------------------------------
// Runtime dtype probe (flag=1 -> fp32 inputs; round 3 confirmed fp32).
// ---------------------------------------------------------------------------
__global__ void detect_k(const u16* __restrict__ x, int* __restrict__ flag)
{
  if (threadIdx.x == 0 && blockIdx.x == 0){
    int sane = 0;
    for (int i = 0; i < 64; ++i){
      int e = (x[i] >> 7) & 0xFF;
      sane += (e >= 100 && e <= 150);
    }
    *flag = (sane < 56) ? 1 : 0;
  }
}

// Canonicalize the 8 small vectors (gammas/betas/biases) to fp32.
// dst layout: [ln1_g 0 | ln1_b 512 | bqkv 1024 | bm 6144 | ln2_g 6656 |
//              ln2_b 7168 | b1 7680 | b2 9728]  total 10240.
__global__ __launch_bounds__(256)
void conv_vecs(const void* a0,const void* a1,const void* a2,const void* a3,
               const void* a4,const void* a5,const void* a6,const void* a7,
               float* __restrict__ dst, const int* __restrict__ flag)
{
  int i = blockIdx.x*256 + threadIdx.x;
  if (i >= 10240) return;
  const void* src; int off;
  if      (i < 512)  { src=a0; off=i; }
  else if (i < 1024) { src=a1; off=i-512; }
  else if (i < 6144) { src=a2; off=i-1024; }
  else if (i < 6656) { src=a3; off=i-6144; }
  else if (i < 7168) { src=a4; off=i-6656; }
  else if (i < 7680) { src=a5; off=i-7168; }
  else if (i < 9728) { src=a6; off=i-7680; }
  else               { src=a7; off=i-9728; }
  dst[i] = (*flag) ? ((const float*)src)[off] : bf2f(((const u16*)src)[off]);
}

// XOR-swizzled chunk index for staging: lane writes LDS chunk c (fixed by HW);
// it must LOAD global chunk (row=c>>3, kc=(c&7)^(row&7)).
#define SWZ_SRC(c) (((c)&7) ^ (((c)>>3)&7))

// ---------------------------------------------------------------------------
// 128x128-tile bf16 GEMM, A row-major (M x K), BT row-major (N x K).
// LDS tiles XOR-swizzled (row stride 64 u16; chunk = (kk*4+quad)^(lane&7)).
// MODE 0: out bf16 = acc + bias
// MODE 2: out bf16 = swish(acc + bias)
// ---------------------------------------------------------------------------
template<int MODE>
__global__ __launch_bounds__(256)
void gemm_bt(const u16* __restrict__ A, const u16* __restrict__ BT,
             void* __restrict__ C, const float* __restrict__ bias,
             int K, int lda, int ldb, int ldc)
{
  __shared__ u16 As[128*64];
  __shared__ u16 Bs[128*64];
  const int tid  = threadIdx.x;
  const int lane = tid & 63;
  const int quad = lane>>4, l7 = lane&7, l15 = lane&15;
  const int wv   = tid >> 6;
  const int wm   = wv >> 1, wn = wv & 1;
  const long m0 = (long)blockIdx.y * 128;
  const long n0 = (long)blockIdx.x * 128;

  f32x4 acc[4][4];
#pragma unroll
  for (int i=0;i<4;i++)
#pragma unroll
    for (int j=0;j<4;j++) acc[i][j] = (f32x4){0.f,0.f,0.f,0.f};

  for (int k0=0; k0<K; k0+=64){
    __syncthreads();
#pragma unroll
    for (int i=0;i<4;i++){
      int c = i*256 + tid;
      gld16(A  + (m0 + (c>>3))*lda + k0 + SWZ_SRC(c)*8, &As[c*8]);
      gld16(BT + (n0 + (c>>3))*ldb + k0 + SWZ_SRC(c)*8, &Bs[c*8]);
    }
    __syncthreads();
#pragma unroll
    for (int kk=0;kk<2;kk++){
      const int ch = ((kk*4 + quad) ^ l7) * 8;
      bf16x8 af[4], bfr[4];
#pragma unroll
      for (int t=0;t<4;t++){
        af[t]  = *(const bf16x8*)&As[(wm*64 + t*16 + l15)*64 + ch];
        bfr[t] = *(const bf16x8*)&Bs[(wn*64 + t*16 + l15)*64 + ch];
      }
#pragma unroll
      for (int ti=0;ti<4;ti++)
#pragma unroll
        for (int tj=0;tj<4;tj++)
          acc[ti][tj] = __builtin_amdgcn_mfma_f32_16x16x32_bf16(af[ti], bfr[tj], acc[ti][tj], 0,0,0);
    }
  }

#pragma unroll
  for (int ti=0;ti<4;ti++)
#pragma unroll
  for (int tj=0;tj<4;tj++)
#pragma unroll
  for (int r=0;r<4;r++){
    long row = m0 + wm*64 + ti*16 + quad*4 + r;
    long col = n0 + wn*64 + tj*16 + l15;
    float v = acc[ti][tj][r] + bias[col];
    if (MODE==2) v = v / (1.f + __expf(-v));
    ((u16*)C)[row*ldc+col] = f2bf(v);
  }
}

// ---------------------------------------------------------------------------
// 128x64-tile bf16 GEMM for narrow-N outputs (N=512). Swizzled LDS.
// MODE 1: out f32 = acc + bias + residual (dtype per flag)   (x2)
// MODE 3: out (dtype per flag) = acc + bias + f32 residual   (final)
// ---------------------------------------------------------------------------
template<int MODE>
__global__ __launch_bounds__(256)
void gemm_n64(const u16* __restrict__ A, const u16* __restrict__ BT,
              void* __restrict__ C, const float* __restrict__ bias,
              const void* __restrict__ res,
              int K, int lda, int ldb, int ldc, const int* __restrict__ flag)
{
  __shared__ u16 As[128*64];
  __shared__ u16 Bs[64*64];
  const int tid  = threadIdx.x;
  const int lane = tid & 63;
  const int quad = lane>>4, l7 = lane&7, l15 = lane&15;
  const int wm   = tid >> 6;          // 4 waves stacked along M (32 rows each)
  const long m0 = (long)blockIdx.y * 128;
  const long n0 = (long)blockIdx.x * 64;
  const bool f32io = flag && (*flag != 0);

  f32x4 acc[2][4];
#pragma unroll
  for (int i=0;i<2;i++)
#pragma unroll
    for (int j=0;j<4;j++) acc[i][j] = (f32x4){0.f,0.f,0.f,0.f};

  for (int k0=0; k0<K; k0+=64){
    __syncthreads();
#pragma unroll
    for (int i=0;i<4;i++){
      int c = i*256 + tid;
      gld16(A + (m0 + (c>>3))*lda + k0 + SWZ_SRC(c)*8, &As[c*8]);
    }
#pragma unroll
    for (int i=0;i<2;i++){
      int c = i*256 + tid;
      gld16(BT + (n0 + (c>>3))*ldb + k0 + SWZ_SRC(c)*8, &Bs[c*8]);
    }
    __syncthreads();
#pragma unroll
    for (int kk=0;kk<2;kk++){
      const int ch = ((kk*4 + quad) ^ l7) * 8;
      bf16x8 af[2], bfr[4];
#pragma unroll
      for (int t=0;t<2;t++)
        af[t]  = *(const bf16x8*)&As[(wm*32 + t*16 + l15)*64 + ch];
#pragma unroll
      for (int t=0;t<4;t++)
        bfr[t] = *(const bf16x8*)&Bs[(t*16 + l15)*64 + ch];
#pragma unroll
      for (int ti=0;ti<2;ti++)
#pragma unroll
        for (int tj=0;tj<4;tj++)
          acc[ti][tj] = __builtin_amdgcn_mfma_f32_16x16x32_bf16(af[ti], bfr[tj], acc[ti][tj], 0,0,0);
    }
  }

#pragma unroll
  for (int ti=0;ti<2;ti++)
#pragma unroll
  for (int tj=0;tj<4;tj++)
#pragma unroll
  for (int r=0;r<4;r++){
    long row = m0 + wm*32 + ti*16 + quad*4 + r;
    long col = n0 + tj*16 + l15;
    float v = acc[ti][tj][r] + bias[col];
    if (MODE==1){
      v += f32io ? ((const float*)res)[row*ldc+col]
                 : bf2f(((const u16*)res)[row*ldc+col]);
      ((float*)C)[row*ldc+col] = v;
    } else {
      v += ((const float*)res)[row*ldc+col];
      if (f32io) ((float*)C)[row*ldc+col] = v;
      else       ((u16*)C)[row*ldc+col]   = f2bf(v);
    }
  }
}

// ---------------------------------------------------------------------------
// Single-pass flash attention: O = softmax(QK^T*scale) @ V with online m/l.
// Block = 512 threads (8 waves); c-width 256; grid (2, 16, 16).
// S-phase: wave wv owns rows wv*16..+15 (8 mfma). Stats in LDS (m/l/alpha).
// PV-phase: wave grid 2x4, O sub-tile 64x64, rescale-by-alpha then accumulate.
// ---------------------------------------------------------------------------
__global__ __launch_bounds__(512, 4)
void att_flash(const u16* __restrict__ qkv, const u16* __restrict__ vt,
               u16* __restrict__ ao)
{
  __shared__ u16 Qs[128*64];   // 16 KB (swizzled)
  __shared__ u16 Ks[64*64];    //  8 KB (swizzled)
  __shared__ u16 Ps[128*68];   // 17 KB (padded rows; b64 reads, bank-floor)
  __shared__ u16 Vs[256*64];   // 32 KB (swizzled)
  __shared__ float m_run[128], l_run[128], alph[128];
  const int tid=threadIdx.x, lane=tid&63, wv=tid>>6;
  const int wm=wv>>2, wn=wv&3;          // PV wave grid 2x4
  const int quad=lane>>4, l7=lane&7, l15=lane&15;
  const int bh=blockIdx.z, b=bh>>3, h=bh&7;
  const long q0=(long)blockIdx.y*128, c0=(long)blockIdx.x*256;
  const u16* qb = qkv + ((long)b*2048 + q0)*5120 + h*64;
  const u16* kb = qkv + (long)b*2048*5120 + 512 + h*64;
  const u16* vb = vt + (long)bh*512*2048;

#pragma unroll
  for (int i=0;i<2;i++){
    int c=i*512+tid;
    gld16(qb + (long)(c>>3)*5120 + SWZ_SRC(c)*8, &Qs[c*8]);
  }
  if (tid<128){ m_run[tid] = -1e30f; l_run[tid] = 0.f; }

  f32x4 o[4][4];
#pragma unroll
  for (int i=0;i<4;i++)
#pragma unroll
    for (int j=0;j<4;j++) o[i][j] = (f32x4){0.f,0.f,0.f,0.f};

  for (int mt=0; mt<32; ++mt){
    const long m0 = (long)mt*64;
    __syncthreads();   // prev PV done; also covers m_run/l_run init on mt==0
    { int c=tid; gld16(kb + (m0 + (c>>3))*5120 + SWZ_SRC(c)*8, &Ks[c*8]); }
#pragma unroll
    for (int i=0;i<4;i++){
      int c=i*512+tid;
      gld16(vb + (c0 + (c>>3))*2048 + m0 + SWZ_SRC(c)*8, &Vs[c*8]);
    }
    __syncthreads();

    // --- S: rows wv*16..+15, cols 0..63 ---
    f32x4 s[4];
#pragma unroll
    for (int j=0;j<4;j++) s[j] = (f32x4){0.f,0.f,0.f,0.f};
#pragma unroll
    for (int kk=0;kk<2;kk++){
      const int ch = ((kk*4 + quad) ^ l7) * 8;
      bf16x8 af = *(const bf16x8*)&Qs[(wv*16 + l15)*64 + ch];
#pragma unroll
      for (int tj=0;tj<4;tj++){
        bf16x8 bfr = *(const bf16x8*)&Ks[(tj*16 + l15)*64 + ch];
        s[tj] = __builtin_amdgcn_mfma_f32_16x16x32_bf16(af, bfr, s[tj], 0,0,0);
      }
    }

    // --- online stats for my 4 rows (row = wv*16 + quad*4 + r) ---
    float nm[4], al[4], rs[4];
#pragma unroll
    for (int r=0;r<4;r++){
      float vm = fmaxf(fmaxf(s[0][r],s[1][r]), fmaxf(s[2][r],s[3][r]));
      vm = fmaxf(vm, __shfl_xor(vm,1)); vm = fmaxf(vm, __shfl_xor(vm,2));
      vm = fmaxf(vm, __shfl_xor(vm,4)); vm = fmaxf(vm, __shfl_xor(vm,8));
      float mo = m_run[wv*16 + quad*4 + r];
      nm[r] = fmaxf(mo, vm*0.125f);
      al[r] = __expf(mo - nm[r]);
      rs[r] = 0.f;
    }
#pragma unroll
    for (int tj=0;tj<4;tj++)
#pragma unroll
    for (int r=0;r<4;r++){
      float pv = __expf(fminf(s[tj][r]*0.125f - nm[r], 0.f));
      rs[r] += pv;
      Ps[(wv*16 + quad*4 + r)*68 + tj*16 + l15] = f2bf(pv);
    }
#pragma unroll
    for (int r=0;r<4;r++){
      rs[r] += __shfl_xor(rs[r],1); rs[r] += __shfl_xor(rs[r],2);
      rs[r] += __shfl_xor(rs[r],4); rs[r] += __shfl_xor(rs[r],8);
    }
    if (l15==0){
#pragma unroll
      for (int r=0;r<4;r++){
        int row = wv*16 + quad*4 + r;
        alph[row]  = al[r];
        m_run[row] = nm[r];
        l_run[row] = l_run[row]*al[r] + rs[r];
      }
    }
    __syncthreads();

    // --- PV: rescale O by alpha, accumulate P(128x64) x V^T(64x256) ---
    float a_[4][4];
#pragma unroll
    for (int ti=0;ti<4;ti++)
#pragma unroll
      for (int r=0;r<4;r++) a_[ti][r] = alph[wm*64 + ti*16 + quad*4 + r];
#pragma unroll
    for (int ti=0;ti<4;ti++)
#pragma unroll
    for (int tj=0;tj<4;tj++)
#pragma unroll
      for (int r=0;r<4;r++) o[ti][tj][r] *= a_[ti][r];

#pragma unroll
    for (int kk=0;kk<2;kk++){
      const int ch = ((kk*4 + quad) ^ l7) * 8;
      bf16x8 af[4], bfr[4];
#pragma unroll
      for (int t=0;t<4;t++){
        int base = (wm*64 + t*16 + l15)*68 + kk*32 + quad*8;
        union { u16x4 hh[2]; bf16x8 v; } u;
        u.hh[0] = *(const u16x4*)&Ps[base];
        u.hh[1] = *(const u16x4*)&Ps[base+4];
        af[t]  = u.v;
        bfr[t] = *(const bf16x8*)&Vs[(wn*64 + t*16 + l15)*64 + ch];
      }
#pragma unroll
      for (int ti=0;ti<4;ti++)
#pragma unroll
        for (int tj=0;tj<4;tj++)
          o[ti][tj] = __builtin_amdgcn_mfma_f32_16x16x32_bf16(af[ti], bfr[tj], o[ti][tj], 0,0,0);
    }
  }

  // epilogue: O /= l
  float rl[4][4];
#pragma unroll
  for (int ti=0;ti<4;ti++)
#pragma unroll
    for (int r=0;r<4;r++) rl[ti][r] = 1.f / l_run[wm*64 + ti*16 + quad*4 + r];
#pragma unroll
  for (int ti=0;ti<4;ti++)
#pragma unroll
  for (int tj=0;tj<4;tj++)
#pragma unroll
  for (int r=0;r<4;r++){
    long rown = q0 + wm*64 + ti*16 + quad*4 + r;
    long col  = c0 + wn*64 + tj*16 + l15;
    ao[((long)b*2048 + rown)*4096 + (long)h*512 + col] = f2bf(o[ti][tj][r]*rl[ti][r]);
  }
}

// ---------------------------------------------------------------------------
// LayerNorm: one wave per row of 512. SRC=0: input dtype per flag (x),
// SRC=1: fp32 input (x2).
// ---------------------------------------------------------------------------
template<int SRC>
__global__ __launch_bounds__(256)
void ln_kernel(const void* __restrict__ xin, const float* __restrict__ g,
               const float* __restrict__ bb, u16* __restrict__ out,
               const int* __restrict__ flag)
{
  const int tid=threadIdx.x, lane=tid&63, wv=tid>>6;
  const long row = (long)blockIdx.x*4 + wv;
  const bool f32 = (SRC==1) || (flag && *flag != 0);
  float v[8];
  if (f32){
    const float* xr = (const float*)xin + row*512 + lane*8;
#pragma unroll
    for (int j=0;j<8;j++) v[j]=xr[j];
  } else {
    const u16* xr = (const u16*)xin + row*512 + lane*8;
    u16x8 xv = *(const u16x8*)xr;
#pragma unroll
    for (int j=0;j<8;j++) v[j]=bf2f(xv[j]);
  }
  float s1=0.f, s2=0.f;
#pragma unroll
  for (int j=0;j<8;j++){ s1+=v[j]; s2+=v[j]*v[j]; }
  for (int off=1; off<64; off<<=1){ s1+=__shfl_xor(s1,off); s2+=__shfl_xor(s2,off); }
  float mu  = s1*(1.f/512.f);
  float var = s2*(1.f/512.f) - mu*mu;
  float rs  = rsqrtf(var + 1e-5f);
  u16x8 ov;
#pragma unroll
  for (int j=0;j<8;j++){
    int col = lane*8+j;
    ov[j] = f2bf((v[j]-mu)*rs*g[col] + bb[col]);
  }
  *(u16x8*)(out + row*512 + lane*8) = ov;
}

// ---------------------------------------------------------------------------
// Tiled transpose -> bf16 out. DUAL: input dtype per flag (weights);
// DUAL=false: bf16 input (vtb). Per-z in-offset (z>>3)*izh+(z&7)*izl (elems).
// ---------------------------------------------------------------------------
template<bool DUAL>
__global__ __launch_bounds__(256)
void transpose_k(const void* __restrict__ in_, u16* __restrict__ out,
                 int ldi, int ldo, long izh, long izl, long oz,
                 const int* __restrict__ flag)
{
  __shared__ u16 t[32][33];
  const int z = blockIdx.z;
  const bool f32 = DUAL && flag && (*flag != 0);
  const long zoff = (long)(z>>3)*izh + (long)(z&7)*izl;
  out += (long)z*oz;
  const int tx = threadIdx.x, ty = threadIdx.y;
  const long c  = (long)blockIdx.x*32 + tx;
  const long r0 = (long)blockIdx.y*32;
  if (f32){
    const float* in = (const float*)in_ + zoff;
#pragma unroll
    for (int j=0;j<4;j++) t[ty+j*8][tx] = f2bf(in[(r0+ty+j*8)*ldi + c]);
  } else {
    const u16* in = (const u16*)in_ + zoff;
#pragma unroll
    for (int j=0;j<4;j++) t[ty+j*8][tx] = in[(r0+ty+j*8)*ldi + c];
  }
  __syncthreads();
  const long rr = r0 + tx;
  const long cc = (long)blockIdx.x*32 + ty;
#pragma unroll
  for (int j=0;j<4;j++) out[(cc+j*8)*ldo + rr] = t[tx][ty+j*8];
}

// ---------------------------------------------------------------------------
extern "C" void kernel_launch(void* const* d_in, const int* in_sizes, int n_in,
                              void* d_out, int out_size, void* d_ws, size_t ws_size,
                              hipStream_t stream)
{
  const void* x    = d_in[0];
  const void* ln1g = d_in[1];
  const void* ln1b = d_in[2];
  const void* Wqkv = d_in[3];
  const void* bqkv = d_in[4];
  const void* Wm   = d_in[5];
  const void* bm   = d_in[6];
  const void* ln2g = d_in[7];
  const void* ln2b = d_in[8];
  const void* W1   = d_in[9];
  const void* b1   = d_in[10];
  const void* W2   = d_in[11];
  const void* b2   = d_in[12];

  char* p = (char*)d_ws;
  auto take = [&](size_t n){ void* r=(void*)p; p += (n + 255) & ~(size_t)255; return r; };
  u16*   lnb   = (u16*)  take((size_t)4096*512*2);       // ln1 out, later ln2 out
  u16*   qkv   = (u16*)  take((size_t)4096*5120*2);      // q|k|v rows; later hb
  u16*   vtb   = (u16*)  take((size_t)16*512*2048*2);    // per-head V^T; later x2
  u16*   wqkvT = (u16*)  take((size_t)5120*512*2);
  u16*   wmT   = (u16*)  take((size_t)512*4096*2);
  u16*   w1T   = (u16*)  take((size_t)2048*512*2);
  u16*   w2T   = (u16*)  take((size_t)512*2048*2);
  u16*   ao    = (u16*)  take((size_t)4096*4096*2);      // attention out (B*N, H*512)
  float* cvec  = (float*)take((size_t)10240*4);          // canonical fp32 small vectors
  int*   flag  = (int*)  take(4);
  float* x2    = (float*)vtb;                            // overlay: vtb dead after att_flash
  u16*   hb    = qkv;                                    // overlay: qkv dead after attention

  // dtype probe + canonical small vectors
  detect_k<<<1, 64, 0, stream>>>((const u16*)x, flag);
  conv_vecs<<<40, 256, 0, stream>>>(ln1g, ln1b, bqkv, bm, ln2g, ln2b, b1, b2, cvec, flag);

  dim3 tb(32,8);
  // Weight transposes (BT-form for the GEMM B operand), dual-dtype
  transpose_k<true><<<dim3(160,16,1), tb, 0, stream>>>(Wqkv, wqkvT, 5120, 512, 0,0,0, flag);
  transpose_k<true><<<dim3(16,128,1), tb, 0, stream>>>(Wm,   wmT,   512, 4096, 0,0,0, flag);
  transpose_k<true><<<dim3(64,16,1),  tb, 0, stream>>>(W1,   w1T,  2048, 512, 0,0,0, flag);
  transpose_k<true><<<dim3(16,64,1),  tb, 0, stream>>>(W2,   w2T,   512, 2048, 0,0,0, flag);

  // ln1 -> qkv
  ln_kernel<0><<<1024, 256, 0, stream>>>(x, cvec+0, cvec+512, lnb, flag);
  gemm_bt<0><<<dim3(40,32), 256, 0, stream>>>(lnb, wqkvT, qkv, cvec+1024, 512, 512, 512, 5120);

  // per-head V^T (bf16 source: our own qkv)
  transpose_k<false><<<dim3(16,64,16), tb, 0, stream>>>(qkv + 1024, vtb, 5120, 2048,
                                                        (long)2048*5120, 512, (long)512*2048, nullptr);
  // fused flash attention (stats + output in one pass)
  att_flash<<<dim3(2,16,16), 512, 0, stream>>>(qkv, vtb, ao);

  // x2 = x + ao@Wm + bm  (fp32; residual dtype per flag)
  gemm_n64<1><<<dim3(8,32), 256, 0, stream>>>(ao, wmT, x2, cvec+6144, x,
                                              4096, 4096, 4096, 512, flag);
  // ln2, MLP
  ln_kernel<1><<<1024, 256, 0, stream>>>(x2, cvec+6656, cvec+7168, lnb, nullptr);
  gemm_bt<2><<<dim3(16,32), 256, 0, stream>>>(lnb, w1T, hb, cvec+7680, 512, 512, 512, 2048);
  gemm_n64<3><<<dim3(8,32), 256, 0, stream>>>(hb, w2T, d_out, cvec+9728, x2,
                                              2048, 2048, 2048, 512, flag);
}